// Round 4
// baseline (419.458 us; speedup 1.0000x reference)
//
#include <hip/hip_runtime.h>
#include <math.h>

// Problem constants
#define Bn    32
#define Tn    2000
#define Mrows (Bn * Tn)        // 64000
#define ENC2n 1024
#define ATTNn 512
#define DECn  512
#define NKn   10
#define KWn   100
#define PADn  50

// workspace layout (floats):
//   [0, 640000)            tmpconv [64000][10]
//   [OFF_DB, +16384)       DB[32][512] = b_enc + dec_e
//   [OFF_SCORE, +64000)    score [64000]
//   [OFF_WT, +262144)      Wt as f16 [512][1024]  (transposed W_enc)
#define OFF_DB    (Mrows * NKn)
#define OFF_SCORE (OFF_DB + Bn * ATTNn)
#define OFF_WT    (OFF_SCORE + Mrows)

typedef _Float16 v8h __attribute__((ext_vector_type(8)));
typedef float f32x4 __attribute__((ext_vector_type(4)));

__device__ __forceinline__ float fast_tanh(float v) {
  const float e = __expf(2.f * v);
  return 1.f - 2.f * __builtin_amdgcn_rcpf(e + 1.f);
}

// ---------------------------------------------------------------------------
// k_wt: W_enc [1024][512] f32 -> Wt [512][1024] f16 (transpose + convert, RNE)
// ---------------------------------------------------------------------------
__global__ __launch_bounds__(256) void k_wt(const float* __restrict__ W,
                                            _Float16* __restrict__ Wt) {
  __shared__ float sh[32][33];
  const int x = threadIdx.x & 31, y = threadIdx.x >> 5;  // y: 0..7
  const int k0 = blockIdx.x * 32, c0 = blockIdx.y * 32;
  for (int i = y; i < 32; i += 8) sh[i][x] = W[(size_t)(k0 + i) * ATTNn + c0 + x];
  __syncthreads();
  for (int i = y; i < 32; i += 8)
    Wt[(size_t)(c0 + i) * ENC2n + k0 + x] = (_Float16)sh[x][i];
}

// ---------------------------------------------------------------------------
// k_conv: tmpconv[b,t,k] = sum_i alpha[b,t+i-50]*Wconv[k,i]; zero score acc
// ---------------------------------------------------------------------------
__global__ __launch_bounds__(256) void k_conv(const float* __restrict__ alpha,
                                              const float* __restrict__ Wconv,
                                              float* __restrict__ ws) {
  __shared__ float sh[256 + KWn - 1];
  __shared__ float wc[NKn * KWn];
  const int b = blockIdx.y;
  const int t0 = blockIdx.x * 256;
  const int tid = threadIdx.x;

  for (int i = tid; i < NKn * KWn; i += 256) wc[i] = Wconv[i];
  const float* __restrict__ arow = alpha + b * Tn;
  for (int i = tid; i < 256 + KWn - 1; i += 256) {
    const int t = t0 - PADn + i;
    sh[i] = (t >= 0 && t < Tn) ? arow[t] : 0.f;
  }
  __syncthreads();

  const int t = t0 + tid;
  if (t < Tn) {
    float acc[NKn];
#pragma unroll
    for (int k = 0; k < NKn; ++k) acc[k] = 0.f;
    for (int i = 0; i < KWn; ++i) {
      const float a = sh[tid + i];
#pragma unroll
      for (int k = 0; k < NKn; ++k) acc[k] = fmaf(a, wc[k * KWn + i], acc[k]);
    }
    float* tp = ws + (size_t)(b * Tn + t) * NKn;
#pragma unroll
    for (int k = 0; k < NKn; ++k) tp[k] = acc[k];
    ws[OFF_SCORE + b * Tn + t] = 0.f;
  }
}

// ---------------------------------------------------------------------------
// k_dec: DB[b,a] = b_enc[a] + sum_d h[b,d]*Wdec[d,a]
// ---------------------------------------------------------------------------
__global__ __launch_bounds__(512) void k_dec(const float* __restrict__ h,
                                             const float* __restrict__ Wdec,
                                             const float* __restrict__ benc,
                                             float* __restrict__ ws) {
  __shared__ float sh[DECn];
  const int b = blockIdx.x;
  const int a = threadIdx.x;
  sh[a] = h[b * DECn + a];
  __syncthreads();
  float acc = 0.f;
  for (int d = 0; d < DECn; ++d) acc = fmaf(sh[d], Wdec[d * ATTNn + a], acc);
  ws[OFF_DB + b * ATTNn + a] = benc[a] + acc;
}

// ---------------------------------------------------------------------------
// k_main: LDS-free fused f16-MFMA GEMM + DB + conv-expansion + tanh + score.
// BM=64 x BN=256, 4 waves; wave wv owns cols wv*64..+64, all waves share the
// 64 A-rows (L1 serves the 4x reuse). MFMA operand fragments are loaded
// DIRECTLY from global: per frag, a wave's 64 lanes read 16 rows x 64 B
// contiguous = 16 fully-consumed cachelines (A f32 via 2x dwordx4 + RNE cvt;
// W f16 via 1x dwordx4, no convert). Register double-buffer prefetches step
// t+1 before the MFMAs of t; raw s_barrier (no vmcnt drain) keeps waves in
// lockstep for L1 locality. No LDS in the loop -> no conflicts, no drains.
// ---------------------------------------------------------------------------
#define BM 64
#define BN 256
#define BK 32
#define NT (ENC2n / BK)   // 32

__global__ __launch_bounds__(256, 3) void k_main(
    const float* __restrict__ A,        // [64000][1024] f32
    const _Float16* __restrict__ Wt,    // [512][1024] f16
    const float* __restrict__ Wc2s,     // [10][512]
    const float* __restrict__ wscore,   // [512]
    float* __restrict__ ws) {
  __shared__ float tcs[BM * NKn];       // 2.5 KB, epilogue only
  const int tid = threadIdx.x;
  const int lane = tid & 63;
  const int wv = tid >> 6;              // wave = column group
  const int lr = lane & 15, lg = lane >> 4;
  const int kk = lg * 8;

  // XCD-chunked bijective swizzle (2000 = 8*250); col pair adjacent in-chunk.
  const int l = blockIdx.x;
  const int lp = (l & 7) * 250 + (l >> 3);
  const int row0 = (lp >> 1) * BM;
  const int c0 = (lp & 1) * BN;

  const float* __restrict__ asrc = A + (size_t)(row0 + lr) * ENC2n + kk;
  const _Float16* __restrict__ wsrc =
      Wt + (size_t)(c0 + wv * 64 + lr) * ENC2n + kk;

  f32x4 acc[4][4];
#pragma unroll
  for (int m = 0; m < 4; ++m)
#pragma unroll
    for (int n = 0; n < 4; ++n) acc[m][n] = (f32x4)0.f;

  // register stage buffers
  float4 as[4][2];
  v8h bs[4];
#pragma unroll
  for (int m = 0; m < 4; ++m) {
    as[m][0] = *(const float4*)(asrc + (size_t)m * 16 * ENC2n);
    as[m][1] = *(const float4*)(asrc + (size_t)m * 16 * ENC2n + 4);
  }
#pragma unroll
  for (int n = 0; n < 4; ++n)
    bs[n] = *(const v8h*)(wsrc + (size_t)n * 16 * ENC2n);

#pragma unroll 2
  for (int t = 0; t < NT; ++t) {
    // move stage -> fragment regs (RNE convert A)
    v8h af[4], bf[4];
#pragma unroll
    for (int m = 0; m < 4; ++m) {
      af[m][0] = (_Float16)as[m][0].x; af[m][1] = (_Float16)as[m][0].y;
      af[m][2] = (_Float16)as[m][0].z; af[m][3] = (_Float16)as[m][0].w;
      af[m][4] = (_Float16)as[m][1].x; af[m][5] = (_Float16)as[m][1].y;
      af[m][6] = (_Float16)as[m][1].z; af[m][7] = (_Float16)as[m][1].w;
    }
#pragma unroll
    for (int n = 0; n < 4; ++n) bf[n] = bs[n];

    // prefetch step t+1 (latency hides under the MFMAs below)
    if (t < NT - 1) {
      const int kn = (t + 1) * BK;
#pragma unroll
      for (int m = 0; m < 4; ++m) {
        as[m][0] = *(const float4*)(asrc + (size_t)m * 16 * ENC2n + kn);
        as[m][1] = *(const float4*)(asrc + (size_t)m * 16 * ENC2n + kn + 4);
      }
#pragma unroll
      for (int n = 0; n < 4; ++n)
        bs[n] = *(const v8h*)(wsrc + (size_t)n * 16 * ENC2n + kn);
    }

    __builtin_amdgcn_s_barrier();   // lockstep for L1 locality; no vmcnt drain

#pragma unroll
    for (int m = 0; m < 4; ++m)
#pragma unroll
      for (int n = 0; n < 4; ++n)
        acc[m][n] = __builtin_amdgcn_mfma_f32_16x16x32_f16(af[m], bf[n],
                                                           acc[m][n], 0, 0, 0);
  }

  // ---- epilogue ----
  {
    const float* __restrict__ tsrc = ws + (size_t)row0 * NKn;
    for (int i = tid; i < BM * NKn; i += 256) tcs[i] = tsrc[i];
  }
  __syncthreads();

  const float* __restrict__ DB = ws + OFF_DB;
  float wc2[4][NKn], wsc[4];
  int cl[4];
#pragma unroll
  for (int fn = 0; fn < 4; ++fn) {
    cl[fn] = c0 + wv * 64 + fn * 16 + lr;
    wsc[fn] = wscore[cl[fn]];
#pragma unroll
    for (int k = 0; k < NKn; ++k) wc2[fn][k] = Wc2s[k * ATTNn + cl[fn]];
  }

#pragma unroll
  for (int fm = 0; fm < 4; ++fm) {
#pragma unroll
    for (int r = 0; r < 4; ++r) {
      const int rowL = fm * 16 + lg * 4 + r;
      const int grow = row0 + rowL;
      const int b = grow / Tn;
      const float* __restrict__ tk = &tcs[rowL * NKn];
      float tkv[NKn];
#pragma unroll
      for (int k = 0; k < NKn; ++k) tkv[k] = tk[k];
      float p = 0.f;
#pragma unroll
      for (int fn = 0; fn < 4; ++fn) {
        float v = acc[fm][fn][r] + DB[b * ATTNn + cl[fn]];
#pragma unroll
        for (int k = 0; k < NKn; ++k) v = fmaf(tkv[k], wc2[fn][k], v);
        p = fmaf(wsc[fn], fast_tanh(v), p);
      }
      p += __shfl_down(p, 8, 16);
      p += __shfl_down(p, 4, 16);
      p += __shfl_down(p, 2, 16);
      p += __shfl_down(p, 1, 16);
      if (lr == 0) atomicAdd(&ws[OFF_SCORE + grow], p);
    }
  }
}

// ---------------------------------------------------------------------------
// k_softmax: masked softmax over T per batch row
// ---------------------------------------------------------------------------
__global__ __launch_bounds__(256) void k_softmax(const float* __restrict__ ws,
                                                 const float* __restrict__ mask,
                                                 float* __restrict__ out) {
  const int b = blockIdx.x, tid = threadIdx.x;
  const float* __restrict__ s = ws + OFF_SCORE + b * Tn;
  const float* __restrict__ mrow = mask + b * Tn;
  float* __restrict__ orow = out + b * Tn;
  __shared__ float red[4];

  float m = -1e30f;
  for (int t = tid; t < Tn; t += 256) m = fmaxf(m, s[t]);
#pragma unroll
  for (int off = 32; off; off >>= 1) m = fmaxf(m, __shfl_down(m, off));
  if ((tid & 63) == 0) red[tid >> 6] = m;
  __syncthreads();
  m = fmaxf(fmaxf(red[0], red[1]), fmaxf(red[2], red[3]));
  __syncthreads();

  float sum = 0.f;
  for (int t = tid; t < Tn; t += 256) {
    const float e = expf(s[t] - m) * mrow[t];
    orow[t] = e;
    sum += e;
  }
#pragma unroll
  for (int off = 32; off; off >>= 1) sum += __shfl_down(sum, off);
  if ((tid & 63) == 0) red[tid >> 6] = sum;
  __syncthreads();
  sum = red[0] + red[1] + red[2] + red[3];
  const float inv = 1.f / sum;
  for (int t = tid; t < Tn; t += 256) orow[t] *= inv;
}

// ---------------------------------------------------------------------------
extern "C" void kernel_launch(void* const* d_in, const int* in_sizes, int n_in,
                              void* d_out, int out_size, void* d_ws, size_t ws_size,
                              hipStream_t stream) {
  const float* enc   = (const float*)d_in[0];
  const float* hid   = (const float*)d_in[1];
  const float* alpha = (const float*)d_in[2];
  const float* mask  = (const float*)d_in[3];
  const float* Wconv = (const float*)d_in[4];
  const float* Wc2s  = (const float*)d_in[5];
  const float* Wenc  = (const float*)d_in[6];
  const float* benc  = (const float*)d_in[7];
  const float* Wdec  = (const float*)d_in[8];
  const float* wscr  = (const float*)d_in[9];
  float* out = (float*)d_out;
  float* ws  = (float*)d_ws;
  _Float16* Wt = (_Float16*)(ws + OFF_WT);

  k_wt<<<dim3(ENC2n / 32, ATTNn / 32), 256, 0, stream>>>(Wenc, Wt);
  k_conv<<<dim3((Tn + 255) / 256, Bn), 256, 0, stream>>>(alpha, Wconv, ws);
  k_dec<<<Bn, DECn, 0, stream>>>(hid, Wdec, benc, ws);
  k_main<<<2000, 256, 0, stream>>>(enc, Wt, Wc2s, wscr, ws);
  k_softmax<<<Bn, 256, 0, stream>>>(ws, mask, out);
}

// Round 5
// 199.204 us; speedup vs baseline: 2.1057x; 2.1057x over previous
//
#include <hip/hip_runtime.h>
#include <math.h>

// Problem constants
#define Bn    32
#define Tn    2000
#define Mrows (Bn * Tn)        // 64000
#define ENC2n 1024
#define ATTNn 512
#define DECn  512
#define NKn   10
#define KWn   100
#define PADn  50

// workspace layout (floats):
//   [0, 640000)            tmpconv [64000][10]
//   [OFF_DB, +16384)       DB[32][512] = b_enc + dec_e
//   [OFF_SCORE, +64000)    score [64000]
//   [OFF_WT, +262144)      Wt as f16 [512][1024]  (transposed W_enc)
#define OFF_DB    (Mrows * NKn)
#define OFF_SCORE (OFF_DB + Bn * ATTNn)
#define OFF_WT    (OFF_SCORE + Mrows)

typedef _Float16 v8h __attribute__((ext_vector_type(8)));
typedef float f32x4 __attribute__((ext_vector_type(4)));

__device__ __forceinline__ float fast_tanh(float v) {
  const float e = __expf(2.f * v);
  return 1.f - 2.f * __builtin_amdgcn_rcpf(e + 1.f);
}

// ---------------------------------------------------------------------------
// k_wt: W_enc [1024][512] f32 -> Wt [512][1024] f16 (transpose + convert, RNE)
// ---------------------------------------------------------------------------
__global__ __launch_bounds__(256) void k_wt(const float* __restrict__ W,
                                            _Float16* __restrict__ Wt) {
  __shared__ float sh[32][33];
  const int x = threadIdx.x & 31, y = threadIdx.x >> 5;  // y: 0..7
  const int k0 = blockIdx.x * 32, c0 = blockIdx.y * 32;
  for (int i = y; i < 32; i += 8) sh[i][x] = W[(size_t)(k0 + i) * ATTNn + c0 + x];
  __syncthreads();
  for (int i = y; i < 32; i += 8)
    Wt[(size_t)(c0 + i) * ENC2n + k0 + x] = (_Float16)sh[x][i];
}

// ---------------------------------------------------------------------------
// k_conv: tmpconv[b,t,k] = sum_i alpha[b,t+i-50]*Wconv[k,i]; zero score acc
// ---------------------------------------------------------------------------
__global__ __launch_bounds__(256) void k_conv(const float* __restrict__ alpha,
                                              const float* __restrict__ Wconv,
                                              float* __restrict__ ws) {
  __shared__ float sh[256 + KWn - 1];
  __shared__ float wc[NKn * KWn];
  const int b = blockIdx.y;
  const int t0 = blockIdx.x * 256;
  const int tid = threadIdx.x;

  for (int i = tid; i < NKn * KWn; i += 256) wc[i] = Wconv[i];
  const float* __restrict__ arow = alpha + b * Tn;
  for (int i = tid; i < 256 + KWn - 1; i += 256) {
    const int t = t0 - PADn + i;
    sh[i] = (t >= 0 && t < Tn) ? arow[t] : 0.f;
  }
  __syncthreads();

  const int t = t0 + tid;
  if (t < Tn) {
    float acc[NKn];
#pragma unroll
    for (int k = 0; k < NKn; ++k) acc[k] = 0.f;
    for (int i = 0; i < KWn; ++i) {
      const float a = sh[tid + i];
#pragma unroll
      for (int k = 0; k < NKn; ++k) acc[k] = fmaf(a, wc[k * KWn + i], acc[k]);
    }
    float* tp = ws + (size_t)(b * Tn + t) * NKn;
#pragma unroll
    for (int k = 0; k < NKn; ++k) tp[k] = acc[k];
    ws[OFF_SCORE + b * Tn + t] = 0.f;
  }
}

// ---------------------------------------------------------------------------
// k_dec: DB[b,a] = b_enc[a] + sum_d h[b,d]*Wdec[d,a]
// ---------------------------------------------------------------------------
__global__ __launch_bounds__(512) void k_dec(const float* __restrict__ h,
                                             const float* __restrict__ Wdec,
                                             const float* __restrict__ benc,
                                             float* __restrict__ ws) {
  __shared__ float sh[DECn];
  const int b = blockIdx.x;
  const int a = threadIdx.x;
  sh[a] = h[b * DECn + a];
  __syncthreads();
  float acc = 0.f;
  for (int d = 0; d < DECn; ++d) acc = fmaf(sh[d], Wdec[d * ATTNn + a], acc);
  ws[OFF_DB + b * ATTNn + a] = benc[a] + acc;
}

// ---------------------------------------------------------------------------
// k_main: fused f16-MFMA GEMM + DB + conv-expansion + tanh + score.
// 128x128 tile, BK=32, 2-DEEP split pipeline (T14): loads for tile t+2 are
// issued at step t; cvt+ds_write of tile t+1 consumes loads issued a full
// tile earlier -> compiler emits COUNTED vmcnt (not 0). Raw s_barrier with
// explicit lgkmcnt(0) only -> no vmcnt drain at the barrier. One barrier per
// tile. s_setprio around the MFMA cluster.
// ---------------------------------------------------------------------------
#define BM 128
#define BN 128
#define BK 32
#define LDKh 40   // 80 B row stride: 16B-aligned, frag reads ~2-way (free)
#define NT (ENC2n / BK)   // 32

#define LOADT(Pa0, Pa1, Pa2, Pa3, Pw0, Pw1, kn)     \
  Pa0 = *(const float4*)(asrc + (kn));              \
  Pa1 = *(const float4*)(asrc + (kn) + 4);          \
  Pa2 = *(const float4*)(asrc + (kn) + 8);          \
  Pa3 = *(const float4*)(asrc + (kn) + 12);         \
  Pw0 = *(const v8h*)(wsrc + (kn));                 \
  Pw1 = *(const v8h*)(wsrc + (kn) + 8);

#define STORET(buf, Pa0, Pa1, Pa2, Pa3, Pw0, Pw1) {                          \
  v8h h0, h1;                                                                \
  h0[0]=(_Float16)Pa0.x; h0[1]=(_Float16)Pa0.y; h0[2]=(_Float16)Pa0.z;       \
  h0[3]=(_Float16)Pa0.w; h0[4]=(_Float16)Pa1.x; h0[5]=(_Float16)Pa1.y;       \
  h0[6]=(_Float16)Pa1.z; h0[7]=(_Float16)Pa1.w;                              \
  h1[0]=(_Float16)Pa2.x; h1[1]=(_Float16)Pa2.y; h1[2]=(_Float16)Pa2.z;       \
  h1[3]=(_Float16)Pa2.w; h1[4]=(_Float16)Pa3.x; h1[5]=(_Float16)Pa3.y;       \
  h1[6]=(_Float16)Pa3.z; h1[7]=(_Float16)Pa3.w;                              \
  *(v8h*)&Asl[buf][sr][sk]     = h0;                                         \
  *(v8h*)&Asl[buf][sr][sk + 8] = h1;                                         \
  *(v8h*)&Wsl[buf][sr][sk]     = Pw0;                                        \
  *(v8h*)&Wsl[buf][sr][sk + 8] = Pw1; }

#define COMPUTET(buf) {                                                      \
  v8h af[4], bf[4];                                                          \
  _Pragma("unroll")                                                          \
  for (int m = 0; m < 4; ++m)                                                \
    af[m] = *(const v8h*)&Asl[buf][wm * 64 + m * 16 + lr][kk];               \
  _Pragma("unroll")                                                          \
  for (int n = 0; n < 4; ++n)                                                \
    bf[n] = *(const v8h*)&Wsl[buf][wn * 64 + n * 16 + lr][kk];               \
  __builtin_amdgcn_s_setprio(1);                                             \
  _Pragma("unroll")                                                          \
  for (int m = 0; m < 4; ++m)                                                \
    _Pragma("unroll")                                                        \
    for (int n = 0; n < 4; ++n)                                              \
      acc[m][n] = __builtin_amdgcn_mfma_f32_16x16x32_f16(af[m], bf[n],       \
                                                         acc[m][n], 0, 0, 0);\
  __builtin_amdgcn_s_setprio(0); }

#define BARRIER() {                                                          \
  asm volatile("s_waitcnt lgkmcnt(0)" ::: "memory");                         \
  __builtin_amdgcn_s_barrier(); }

__global__ __launch_bounds__(256, 3) void k_main(
    const float* __restrict__ A,        // [64000][1024] f32
    const _Float16* __restrict__ Wt,    // [512][1024] f16
    const float* __restrict__ Wc2s,     // [10][512]
    const float* __restrict__ wscore,   // [512]
    float* __restrict__ ws) {
  __shared__ _Float16 Asl[2][BM][LDKh];   // 20 KB
  __shared__ _Float16 Wsl[2][BN][LDKh];   // 20 KB
  const int tid = threadIdx.x;
  const int lane = tid & 63;
  const int wv = tid >> 6;
  const int wm = wv >> 1, wn = wv & 1;

  // XCD-chunked bijective swizzle (2000 = 8*250); 4 col-blocks of a row
  // panel adjacent within a chunk -> A panel fetched ~once per XCD/L2.
  const int l = blockIdx.x;
  const int lp = (l & 7) * 250 + (l >> 3);
  const int row0 = (lp >> 2) * BM;
  const int c0 = (lp & 3) * BN;

  // staging map: thread -> row sr = tid>>1, k-offset sk = (tid&1)*16
  const int sr = tid >> 1, sk = (tid & 1) * 16;
  const float* __restrict__ asrc = A + (size_t)(row0 + sr) * ENC2n + sk;
  const _Float16* __restrict__ wsrc = Wt + (size_t)(c0 + sr) * ENC2n + sk;

  const int lr = lane & 15, lg = lane >> 4;
  const int kk = lg * 8;

  f32x4 acc[4][4];
#pragma unroll
  for (int m = 0; m < 4; ++m)
#pragma unroll
    for (int n = 0; n < 4; ++n) acc[m][n] = (f32x4)0.f;

  // two register batches (A: 4xfloat4, W: 2xv8h each)
  float4 xa0, xa1, xa2, xa3; v8h xw0, xw1;   // batch X
  float4 ya0, ya1, ya2, ya3; v8h yw0, yw1;   // batch Y

  // ---- prologue: tiles 0,1 in flight; tile 0 -> lds0 ----
  LOADT(xa0, xa1, xa2, xa3, xw0, xw1, 0);
  LOADT(ya0, ya1, ya2, ya3, yw0, yw1, BK);
  STORET(0, xa0, xa1, xa2, xa3, xw0, xw1);
  BARRIER();

  // ---- main: 2 tiles per iteration, 1 barrier per tile ----
  for (int t = 0; t < NT - 2; t += 2) {
    LOADT(xa0, xa1, xa2, xa3, xw0, xw1, (t + 2) * BK);
    COMPUTET(0);                                   // tile t
    STORET(1, ya0, ya1, ya2, ya3, yw0, yw1);       // tile t+1 -> lds1
    BARRIER();
    LOADT(ya0, ya1, ya2, ya3, yw0, yw1, (t + 3) * BK);
    COMPUTET(1);                                   // tile t+1
    STORET(0, xa0, xa1, xa2, xa3, xw0, xw1);       // tile t+2 -> lds0
    BARRIER();
  }
  // tiles NT-2 (lds0) and NT-1 (batch Y)
  COMPUTET(0);
  STORET(1, ya0, ya1, ya2, ya3, yw0, yw1);
  BARRIER();
  COMPUTET(1);

  // ---- epilogue ----
  __syncthreads();
  float* tcs = (float*)&Asl[0][0][0];     // reuse LDS: tmpconv slice [128][10]
  {
    const float* __restrict__ tsrc = ws + (size_t)row0 * NKn;
    for (int i = tid; i < BM * NKn; i += 256) tcs[i] = tsrc[i];
  }
  __syncthreads();

  const float* __restrict__ DB = ws + OFF_DB;
  float wc2[4][NKn], wsc[4];
  int cl[4];
#pragma unroll
  for (int fn = 0; fn < 4; ++fn) {
    cl[fn] = c0 + wn * 64 + fn * 16 + lr;
    wsc[fn] = wscore[cl[fn]];
#pragma unroll
    for (int k = 0; k < NKn; ++k) wc2[fn][k] = Wc2s[k * ATTNn + cl[fn]];
  }

#pragma unroll
  for (int fm = 0; fm < 4; ++fm) {
#pragma unroll
    for (int r = 0; r < 4; ++r) {
      const int rowL = wm * 64 + fm * 16 + lg * 4 + r;
      const int grow = row0 + rowL;
      const int b = grow / Tn;
      const float* __restrict__ tk = &tcs[rowL * NKn];
      float tkv[NKn];
#pragma unroll
      for (int k = 0; k < NKn; ++k) tkv[k] = tk[k];
      float p = 0.f;
#pragma unroll
      for (int fn = 0; fn < 4; ++fn) {
        float v = acc[fm][fn][r] + DB[b * ATTNn + cl[fn]];
#pragma unroll
        for (int k = 0; k < NKn; ++k) v = fmaf(tkv[k], wc2[fn][k], v);
        p = fmaf(wsc[fn], fast_tanh(v), p);
      }
      p += __shfl_down(p, 8, 16);
      p += __shfl_down(p, 4, 16);
      p += __shfl_down(p, 2, 16);
      p += __shfl_down(p, 1, 16);
      if (lr == 0) atomicAdd(&ws[OFF_SCORE + grow], p);
    }
  }
}

// ---------------------------------------------------------------------------
// k_softmax: masked softmax over T per batch row
// ---------------------------------------------------------------------------
__global__ __launch_bounds__(256) void k_softmax(const float* __restrict__ ws,
                                                 const float* __restrict__ mask,
                                                 float* __restrict__ out) {
  const int b = blockIdx.x, tid = threadIdx.x;
  const float* __restrict__ s = ws + OFF_SCORE + b * Tn;
  const float* __restrict__ mrow = mask + b * Tn;
  float* __restrict__ orow = out + b * Tn;
  __shared__ float red[4];

  float m = -1e30f;
  for (int t = tid; t < Tn; t += 256) m = fmaxf(m, s[t]);
#pragma unroll
  for (int off = 32; off; off >>= 1) m = fmaxf(m, __shfl_down(m, off));
  if ((tid & 63) == 0) red[tid >> 6] = m;
  __syncthreads();
  m = fmaxf(fmaxf(red[0], red[1]), fmaxf(red[2], red[3]));
  __syncthreads();

  float sum = 0.f;
  for (int t = tid; t < Tn; t += 256) {
    const float e = expf(s[t] - m) * mrow[t];
    orow[t] = e;
    sum += e;
  }
#pragma unroll
  for (int off = 32; off; off >>= 1) sum += __shfl_down(sum, off);
  if ((tid & 63) == 0) red[tid >> 6] = sum;
  __syncthreads();
  sum = red[0] + red[1] + red[2] + red[3];
  const float inv = 1.f / sum;
  for (int t = tid; t < Tn; t += 256) orow[t] *= inv;
}

// ---------------------------------------------------------------------------
extern "C" void kernel_launch(void* const* d_in, const int* in_sizes, int n_in,
                              void* d_out, int out_size, void* d_ws, size_t ws_size,
                              hipStream_t stream) {
  const float* enc   = (const float*)d_in[0];
  const float* hid   = (const float*)d_in[1];
  const float* alpha = (const float*)d_in[2];
  const float* mask  = (const float*)d_in[3];
  const float* Wconv = (const float*)d_in[4];
  const float* Wc2s  = (const float*)d_in[5];
  const float* Wenc  = (const float*)d_in[6];
  const float* benc  = (const float*)d_in[7];
  const float* Wdec  = (const float*)d_in[8];
  const float* wscr  = (const float*)d_in[9];
  float* out = (float*)d_out;
  float* ws  = (float*)d_ws;
  _Float16* Wt = (_Float16*)(ws + OFF_WT);

  k_wt<<<dim3(ENC2n / 32, ATTNn / 32), 256, 0, stream>>>(Wenc, Wt);
  k_conv<<<dim3((Tn + 255) / 256, Bn), 256, 0, stream>>>(alpha, Wconv, ws);
  k_dec<<<Bn, DECn, 0, stream>>>(hid, Wdec, benc, ws);
  k_main<<<2000, 256, 0, stream>>>(enc, Wt, Wc2s, wscr, ws);
  k_softmax<<<Bn, 256, 0, stream>>>(ws, mask, out);
}